// Round 11
// baseline (392.849 us; speedup 1.0000x reference)
//
#include <hip/hip_runtime.h>
#include <hip/hip_bf16.h>
#include <stdint.h>

#define NB 8
#define NC 512
#define NN 4096
#define ND 64

typedef __attribute__((ext_vector_type(8))) short short8;
typedef __attribute__((ext_vector_type(4))) float f32x4;

#define LOG2E 1.44269504088896340736f

static __device__ __forceinline__ uint32_t cvt_pk_bf16(float lo, float hi) {
    uint32_t r;
    asm("v_cvt_pk_bf16_f32 %0, %1, %2" : "=v"(r) : "v"(lo), "v"(hi));
    return r;
}

// barrier that drains LDS ops only — global loads stay in flight (T4)
static __device__ __forceinline__ void barrier_lgkm() {
    asm volatile("s_waitcnt lgkmcnt(0)" ::: "memory");
    __builtin_amdgcn_s_barrier();
    __builtin_amdgcn_sched_barrier(0);
}

// ---------------- Kernel 0: W fp32 -> bf16 (LOG2E baked into q rows) --------
__global__ __launch_bounds__(256) void wprep(
    const float* __restrict__ wq, const float* __restrict__ wk,
    const float* __restrict__ wv, unsigned short* __restrict__ Wbf)
{
    const int g = blockIdx.x * 256 + threadIdx.x;
    const int o = g >> 6;
    const int c = (g & 63) << 3;
    const float* src; float sc;
    if (o < 64)       { src = wq + (size_t)o*NC;        sc = LOG2E; }
    else if (o < 128) { src = wk + (size_t)(o-64)*NC;   sc = 1.f; }
    else              { src = wv + (size_t)(o-128)*NC;  sc = 1.f; }
    float4 a = *reinterpret_cast<const float4*>(src + c);
    float4 d = *reinterpret_cast<const float4*>(src + c + 4);
    uint4 r;
    r.x = cvt_pk_bf16(a.x*sc, a.y*sc);
    r.y = cvt_pk_bf16(a.z*sc, a.w*sc);
    r.z = cvt_pk_bf16(d.x*sc, d.y*sc);
    r.w = cvt_pk_bf16(d.z*sc, d.w*sc);
    *reinterpret_cast<uint4*>(Wbf + (size_t)o*NC + c) = r;
}

// ---------------- Kernel A: fused QKV projection ----------------------------
__global__ __launch_bounds__(256, 2) void qkv_proj(
    const float* __restrict__ x,
    const unsigned short* __restrict__ Wbf,
    const float* __restrict__ bq, const float* __restrict__ bk,
    const float* __restrict__ bv,
    unsigned short* __restrict__ QT, unsigned short* __restrict__ KT,
    unsigned char* __restrict__ V)
{
    const int nblk = blockIdx.x;
    const int b    = blockIdx.y;
    const int t = threadIdx.x;
    const int wid = t >> 6;
    const int l = t & 63;
    const int lg = l >> 4, lr = l & 15;
    const int n0 = nblk * 64;
    const float* xb = x + (size_t)b * NC * NN;

    __shared__ unsigned short XT[2][64][72];

    const int o_base = wid * 160;

    f32x4 acc[10][4];
    #pragma unroll
    for (int mt = 0; mt < 10; ++mt) {
        const int ob = o_base + mt*16;
        #pragma unroll
        for (int bb = 0; bb < 4; ++bb) {
            const int o = ob + lg*4 + bb;
            float bias = (ob < 64) ? bq[o]*LOG2E : (ob < 128) ? bk[o-64] : bv[o-128];
            #pragma unroll
            for (int nt = 0; nt < 4; ++nt) acc[mt][nt][bb] = bias;
        }
    }

    const int cq = (t >> 4) << 2;
    const int n4 = (t & 15) << 2;
    float4 xs0, xs1, xs2, xs3;
    auto xload = [&](int ks) {
        const float* xr = xb + (size_t)(ks*64 + cq)*NN + n0 + n4;
        xs0 = *reinterpret_cast<const float4*>(xr);
        xs1 = *reinterpret_cast<const float4*>(xr + NN);
        xs2 = *reinterpret_cast<const float4*>(xr + 2*(size_t)NN);
        xs3 = *reinterpret_cast<const float4*>(xr + 3*(size_t)NN);
    };
    auto xwrite = [&](int buf) {
        uint2 w;
        w.x = cvt_pk_bf16(xs0.x, xs1.x); w.y = cvt_pk_bf16(xs2.x, xs3.x);
        *reinterpret_cast<uint2*>(&XT[buf][n4+0][cq]) = w;
        w.x = cvt_pk_bf16(xs0.y, xs1.y); w.y = cvt_pk_bf16(xs2.y, xs3.y);
        *reinterpret_cast<uint2*>(&XT[buf][n4+1][cq]) = w;
        w.x = cvt_pk_bf16(xs0.z, xs1.z); w.y = cvt_pk_bf16(xs2.z, xs3.z);
        *reinterpret_cast<uint2*>(&XT[buf][n4+2][cq]) = w;
        w.x = cvt_pk_bf16(xs0.w, xs1.w); w.y = cvt_pk_bf16(xs2.w, xs3.w);
        *reinterpret_cast<uint2*>(&XT[buf][n4+3][cq]) = w;
    };

    xload(0);
    xwrite(0);
    __syncthreads();

    for (int ks = 0; ks < 8; ++ks) {
        const int buf = ks & 1;
        const int c0 = ks * 64;
        if (ks < 7) xload(ks + 1);
        #pragma unroll
        for (int k2 = 0; k2 < 2; ++k2) {
            short8 bf[4];
            #pragma unroll
            for (int nt = 0; nt < 4; ++nt)
                bf[nt] = *reinterpret_cast<const short8*>(&XT[buf][nt*16 + lr][k2*32 + lg*8]);
            #pragma unroll
            for (int mt = 0; mt < 10; ++mt) {
                short8 af = *reinterpret_cast<const short8*>(
                    Wbf + (size_t)(o_base + mt*16 + lr)*NC + c0 + k2*32 + lg*8);
                #pragma unroll
                for (int nt = 0; nt < 4; ++nt)
                    acc[mt][nt] = __builtin_amdgcn_mfma_f32_16x16x32_bf16(af, bf[nt], acc[mt][nt], 0, 0, 0);
            }
        }
        if (ks < 7) xwrite(buf ^ 1);
        __syncthreads();
    }

    #pragma unroll
    for (int mt = 0; mt < 10; ++mt) {
        const int ob = o_base + mt*16;
        const int ol = ob + lg*4;
        #pragma unroll
        for (int nt = 0; nt < 4; ++nt) {
            const int n = n0 + nt*16 + lr;
            if (ob < 128) {
                uint2 pk;
                pk.x = cvt_pk_bf16(acc[mt][nt][0], acc[mt][nt][1]);
                pk.y = cvt_pk_bf16(acc[mt][nt][2], acc[mt][nt][3]);
                unsigned short* dst = (ob < 64) ? (QT + ((size_t)b*NN + n)*ND + ol)
                                                : (KT + ((size_t)b*NN + n)*ND + (ol - 64));
                *reinterpret_cast<uint2*>(dst) = pk;
            } else {
                const int c = ol - 128;
                #pragma unroll
                for (int bb = 0; bb < 4; ++bb) {
                    int v8 = __builtin_amdgcn_cvt_pk_fp8_f32(acc[mt][nt][bb], 0.f, 0, false);
                    V[((size_t)b*NC + c + bb)*NN + n] = (unsigned char)(v8 & 0xff);
                }
            }
        }
    }
}

// ---------------- Kernel S: pass-1 row-max (max only, no online chain) ------
// 256 blocks x 8 waves x 16 rows. K LDS-staged (lag-1 dbuf, 1 lgkm barrier
// per tile). Per tile: 8 MFMA + 16 elementwise fmax. Cross-lane reduce ONCE
// at the end. MFMA determinism => pass-2 recomputes identical S.
__global__ __launch_bounds__(512) void stats(
    const unsigned short* __restrict__ QT,
    const unsigned short* __restrict__ KT,
    float* __restrict__ Mst)
{
    const int bi = blockIdx.x;
    const int b  = bi & 7;
    const int n0 = (bi >> 3) * 128;
    const int t = threadIdx.x;
    const int wid = t >> 6;
    const int l = t & 63;
    const int lg = l >> 4, lr = l & 15;

    __shared__ __align__(16) unsigned short Klds[2*64*64];   // 16 KB dbuf

    const unsigned short* Qb = QT + ((size_t)b*NN + n0)*ND;
    const unsigned short* Kb = KT + (size_t)b*NN*ND;

    short8 qf0 = *reinterpret_cast<const short8*>(Qb + (size_t)(16*wid + lr)*ND + lg*8);
    short8 qf1 = *reinterpret_cast<const short8*>(Qb + (size_t)(16*wid + lr)*ND + 32 + lg*8);

    const int krow = t >> 3;
    const int kdst = krow*64 + ((8*(t & 7)) ^ (8*(krow & 7)));
    {
        short8 k0 = *reinterpret_cast<const short8*>(Kb + (size_t)t*8);
        *reinterpret_cast<short8*>(&Klds[kdst]) = k0;
    }

    const int kswz = 8*(lr & 7);
    f32x4 mr = f32x4{-1e30f, -1e30f, -1e30f, -1e30f};

    barrier_lgkm();

    for (int i = 0; i < 64; ++i) {
        short8 kr;
        if (i < 63)
            kr = *reinterpret_cast<const short8*>(Kb + (size_t)(i+1)*4096 + t*8);

        const unsigned short* kbuf = &Klds[(i & 1)*4096];
        #pragma unroll
        for (int j = 0; j < 4; ++j) {
            const unsigned short* kp = kbuf + (16*j + lr)*64;
            short8 a0 = *reinterpret_cast<const short8*>(kp + ((8*lg) ^ kswz));
            short8 a1 = *reinterpret_cast<const short8*>(kp + ((32 + 8*lg) ^ kswz));
            f32x4 acc = __builtin_amdgcn_mfma_f32_16x16x32_bf16(a0, qf0, f32x4{0.f,0.f,0.f,0.f}, 0, 0, 0);
            acc = __builtin_amdgcn_mfma_f32_16x16x32_bf16(a1, qf1, acc, 0, 0, 0);
            mr[0] = fmaxf(mr[0], acc[0]);
            mr[1] = fmaxf(mr[1], acc[1]);
            mr[2] = fmaxf(mr[2], acc[2]);
            mr[3] = fmaxf(mr[3], acc[3]);
        }
        if (i < 63)
            *reinterpret_cast<short8*>(&Klds[((i+1) & 1)*4096 + kdst]) = kr;
        barrier_lgkm();
    }

    float mx = fmaxf(fmaxf(mr[0], mr[1]), fmaxf(mr[2], mr[3]));
    mx = fmaxf(mx, __shfl_xor(mx, 16));
    mx = fmaxf(mx, __shfl_xor(mx, 32));
    if (lg == 0) Mst[(size_t)b*NN + n0 + 16*wid + lr] = mx;
}

// ---------------- Kernel B: pass-2 — P=exp2(S-M), PV, L in-loop, residual ---
// M=64 q/block, 8 waves, 512 blocks = 2 blocks/CU (launch_bounds(512,4) caps
// regs at 128 incl AGPR -> 4 waves/SIMD, independent barrier groups).
// QK (m-group x s-group)-split: wave (mg,sg) computes S^T[32sg..+32][16mg..+16]
// (4 MFMA). PV c-split 64c/wave (32 MFMA). L accumulated per-lane in EXPK.
__global__ __launch_bounds__(512, 4) void attn(
    const unsigned short* __restrict__ QT,
    const unsigned short* __restrict__ KT,
    const unsigned char* __restrict__ V,
    const float* __restrict__ Mst,
    const float* __restrict__ x,
    const float* __restrict__ alpha_p,
    float* __restrict__ out)
{
    const int bi = blockIdx.x;
    const int b  = bi & 7;            // batch per XCD (L2 locality)
    const int n0 = (bi >> 3) * 64;
    const int t = threadIdx.x;
    const int wid = t >> 6;           // 0..7: PV c-slice owner
    const int mg  = wid >> 1;         // 0..3: QK m-group
    const int sg  = wid & 1;          // 0..1: QK s-group
    const int l = t & 63;
    const int lg = l >> 4, lr = l & 15;

    __shared__ __align__(16) unsigned short Klds[2*64*64];   // 16 KB, swizzled
    __shared__ __align__(16) unsigned char  Plds[2*64*128];  // 16 KB, swizzled
    __shared__ float Lp[2][64];

    const unsigned short* Qb = QT + ((size_t)b*NN + n0)*ND;
    const unsigned short* Kb = KT + (size_t)b*NN*ND;
    const unsigned char*  Vb = V + ((size_t)b*NC + 64*wid)*NN;

    // Q B-frags for this wave's QK rows m = 16*mg + lr
    short8 qf0 = *reinterpret_cast<const short8*>(Qb + (size_t)(16*mg + lr)*ND + lg*8);
    short8 qf1 = *reinterpret_cast<const short8*>(Qb + (size_t)(16*mg + lr)*ND + 32 + lg*8);
    const float Mreg = Mst[(size_t)b*NN + n0 + 16*mg + lr];

    const int krow = t >> 3;
    const int kdst = krow*64 + ((8*(t & 7)) ^ (8*(krow & 7)));
    {   // stage K(0) -> slot0
        short8 k0 = *reinterpret_cast<const short8*>(Kb + (size_t)t*8);
        *reinterpret_cast<short8*>(&Klds[kdst]) = k0;
    }

    f32x4 oacc[4][4];   // rows m=16mt+4lg+bb, cols c=64wid+16ct+lr
    #pragma unroll
    for (int mt = 0; mt < 4; ++mt)
        #pragma unroll
        for (int ct = 0; ct < 4; ++ct)
            oacc[mt][ct] = f32x4{0.f, 0.f, 0.f, 0.f};

    float lrun = 0.f;

    long vf[4];
    #pragma unroll
    for (int ct = 0; ct < 4; ++ct)
        vf[ct] = *reinterpret_cast<const long*>(Vb + (size_t)(ct*16 + lr)*NN + 8*lg);

    barrier_lgkm();   // K(0) visible

    const int kswz = 8*(lr & 7);
    const int pswz = 8*lr;
    const int prow = (16*mg + lr) * 128;   // EXPK write row

    auto PVstep = [&](const unsigned char* pbase, int k2, int s_pref) {
        long vfn[4];
        #pragma unroll
        for (int ct = 0; ct < 4; ++ct)
            vfn[ct] = *reinterpret_cast<const long*>(
                Vb + (size_t)(ct*16 + lr)*NN + s_pref + 8*lg);
        long pf[4];
        #pragma unroll
        for (int mt = 0; mt < 4; ++mt)
            pf[mt] = *reinterpret_cast<const long*>(
                pbase + (16*mt + lr)*128 + ((k2*32 + 8*lg) ^ pswz));
        __builtin_amdgcn_s_setprio(1);
        #pragma unroll
        for (int mt = 0; mt < 4; ++mt)
            #pragma unroll
            for (int ct = 0; ct < 4; ++ct)
                oacc[mt][ct] = __builtin_amdgcn_mfma_f32_16x16x32_fp8_fp8(
                    pf[mt], vf[ct], oacc[mt][ct], 0, 0, 0);
        __builtin_amdgcn_s_setprio(0);
        #pragma unroll
        for (int ct = 0; ct < 4; ++ct) vf[ct] = vfn[ct];
    };

    // QK^T for this wave's (mg, sg) sub-block: sn[j] = S^T[32sg+16j+4lg+bb][16mg+lr]
    auto QKt = [&](const unsigned short* kbuf, f32x4 (&sn)[2]) {
        #pragma unroll
        for (int j = 0; j < 2; ++j) {
            const unsigned short* kp = kbuf + (32*sg + 16*j + lr)*64;
            short8 a0 = *reinterpret_cast<const short8*>(kp + ((8*lg) ^ kswz));
            short8 a1 = *reinterpret_cast<const short8*>(kp + ((32 + 8*lg) ^ kswz));
            sn[j] = __builtin_amdgcn_mfma_f32_16x16x32_bf16(a0, qf0, f32x4{0.f,0.f,0.f,0.f}, 0, 0, 0);
            sn[j] = __builtin_amdgcn_mfma_f32_16x16x32_bf16(a1, qf1, sn[j], 0, 0, 0);
        }
    };

    // exp + fp8-pack + LDS write + per-lane L accumulation (no stats chain)
    auto EXPK = [&](const f32x4 (&sn)[2], unsigned char* pb) {
        #pragma unroll
        for (int j = 0; j < 2; ++j) {
            float p0 = __builtin_amdgcn_exp2f(sn[j][0] - Mreg);
            float p1 = __builtin_amdgcn_exp2f(sn[j][1] - Mreg);
            float p2 = __builtin_amdgcn_exp2f(sn[j][2] - Mreg);
            float p3 = __builtin_amdgcn_exp2f(sn[j][3] - Mreg);
            lrun += (p0 + p1) + (p2 + p3);
            int d = __builtin_amdgcn_cvt_pk_fp8_f32(p0, p1, 0, false);
            d = __builtin_amdgcn_cvt_pk_fp8_f32(p2, p3, d, true);
            *reinterpret_cast<int*>(&pb[prow + ((32*sg + 16*j + 4*lg) ^ pswz)]) = d;
        }
    };

    // ---- prologue: P(0) from slot0; stage K(1) -> slot1 ----
    {
        f32x4 sac[2];
        QKt(&Klds[0], sac);
        short8 kr = *reinterpret_cast<const short8*>(Kb + 4096 + (size_t)t*8);  // K(1)
        EXPK(sac, Plds);
        *reinterpret_cast<short8*>(&Klds[4096 + kdst]) = kr;
    }
    barrier_lgkm();   // P(0), K(1) visible

    // ---- main loop over 64-key tiles ----
    for (int i = 0; i < 63; ++i) {
        const int cur = i & 1, nxt = cur ^ 1;
        const unsigned char* pcur = Plds + cur*8192;
        unsigned char* pnxt = Plds + nxt*8192;
        const int s0 = i * 64;
        const int ipre = (i + 2 < 64) ? (i + 2) : 63;

        // K(i+2) issue-early (LDS write at iter end; in flight across phases)
        short8 kr = *reinterpret_cast<const short8*>(Kb + (size_t)ipre*4096 + t*8);

        f32x4 sn[2];
        QKt(&Klds[nxt*4096], sn);          // QK^T(i+1), 4 MFMA

        PVstep(pcur, 0, s0 + 32);          // PV(i) k2=0; prefetch V k2=1
        EXPK(sn, pnxt);                    // P(i+1) -> LDS (overlaps PV)
        PVstep(pcur, 1, s0 + 64);          // PV(i) k2=1; prefetch next-tile V

        *reinterpret_cast<short8*>(&Klds[cur*4096 + kdst]) = kr;   // K(i+2)

        barrier_lgkm();   // LDS-only drain: V prefetches stay in flight
    }

    // ---- tail: PV(63) ----
    {
        const unsigned char* pcur = Plds + 8192;    // 63 & 1 = 1
        const int s0 = 63 * 64;
        PVstep(pcur, 0, s0 + 32);
        PVstep(pcur, 1, s0);               // dummy prefetch
    }

    // ---- finalize L: per-lane sums -> cross-lane -> LDS -> epilogue ----
    lrun += __shfl_xor(lrun, 16);
    lrun += __shfl_xor(lrun, 32);
    if (lg == 0) Lp[sg][16*mg + lr] = lrun;
    __syncthreads();

    const float alpha = alpha_p[0];
    #pragma unroll
    for (int mt = 0; mt < 4; ++mt) {
        float4 la = *reinterpret_cast<const float4*>(&Lp[0][16*mt + 4*lg]);
        float4 lb = *reinterpret_cast<const float4*>(&Lp[1][16*mt + 4*lg]);
        float ar0 = alpha / (la.x + lb.x);
        float ar1 = alpha / (la.y + lb.y);
        float ar2 = alpha / (la.z + lb.z);
        float ar3 = alpha / (la.w + lb.w);
        #pragma unroll
        for (int ct = 0; ct < 4; ++ct) {
            const int c = 64*wid + 16*ct + lr;
            const size_t base = ((size_t)b*NC + c)*NN + n0 + 16*mt + 4*lg;
            float4 x4 = *reinterpret_cast<const float4*>(x + base);
            float4 o4;
            o4.x = oacc[mt][ct][0] * ar0 + x4.x;
            o4.y = oacc[mt][ct][1] * ar1 + x4.y;
            o4.z = oacc[mt][ct][2] * ar2 + x4.z;
            o4.w = oacc[mt][ct][3] * ar3 + x4.w;
            *reinterpret_cast<float4*>(out + base) = o4;
        }
    }
}

extern "C" void kernel_launch(void* const* d_in, const int* in_sizes, int n_in,
                              void* d_out, int out_size, void* d_ws, size_t ws_size,
                              hipStream_t stream) {
    const float* x     = (const float*)d_in[0];
    const float* wq    = (const float*)d_in[1];
    const float* bq    = (const float*)d_in[2];
    const float* wk    = (const float*)d_in[3];
    const float* bk    = (const float*)d_in[4];
    const float* wv    = (const float*)d_in[5];
    const float* bv    = (const float*)d_in[6];
    const float* alpha = (const float*)d_in[7];

    // ws: QT bf16 4MB | KT bf16 4MB | V fp8 16MB | Wbf bf16 640KB | M 128KB
    unsigned short* QT = (unsigned short*)d_ws;
    unsigned short* KT = QT + (size_t)NB*NN*ND;
    unsigned char*  V  = (unsigned char*)(KT + (size_t)NB*NN*ND);
    unsigned short* Wbf = (unsigned short*)(V + (size_t)NB*NC*NN);
    float* Mst = (float*)(Wbf + (size_t)640*NC);

    wprep<<<160, 256, 0, stream>>>(wq, wk, wv, Wbf);
    dim3 gA(64, 8);
    qkv_proj<<<gA, 256, 0, stream>>>(x, Wbf, bq, bk, bv, QT, KT, V);
    stats<<<NB * (NN/128), 512, 0, stream>>>(QT, KT, Mst);
    attn<<<NB * (NN/64), 512, 0, stream>>>(QT, KT, V, Mst, x, alpha, (float*)d_out);
}

// Round 12
// 222.544 us; speedup vs baseline: 1.7653x; 1.7653x over previous
//
#include <hip/hip_runtime.h>
#include <hip/hip_bf16.h>
#include <stdint.h>

#define NB 8
#define NC 512
#define NN 4096
#define ND 64

typedef __attribute__((ext_vector_type(8))) short short8;
typedef __attribute__((ext_vector_type(4))) float f32x4;

#define LOG2E 1.44269504088896340736f

static __device__ __forceinline__ uint32_t cvt_pk_bf16(float lo, float hi) {
    uint32_t r;
    asm("v_cvt_pk_bf16_f32 %0, %1, %2" : "=v"(r) : "v"(lo), "v"(hi));
    return r;
}

// barrier that drains LDS ops only — global loads stay in flight (T4)
static __device__ __forceinline__ void barrier_lgkm() {
    asm volatile("s_waitcnt lgkmcnt(0)" ::: "memory");
    __builtin_amdgcn_s_barrier();
    __builtin_amdgcn_sched_barrier(0);
}

// ---------------- Kernel 0: W fp32 -> bf16 (LOG2E baked into q rows) --------
__global__ __launch_bounds__(256) void wprep(
    const float* __restrict__ wq, const float* __restrict__ wk,
    const float* __restrict__ wv, unsigned short* __restrict__ Wbf)
{
    const int g = blockIdx.x * 256 + threadIdx.x;
    const int o = g >> 6;
    const int c = (g & 63) << 3;
    const float* src; float sc;
    if (o < 64)       { src = wq + (size_t)o*NC;        sc = LOG2E; }
    else if (o < 128) { src = wk + (size_t)(o-64)*NC;   sc = 1.f; }
    else              { src = wv + (size_t)(o-128)*NC;  sc = 1.f; }
    float4 a = *reinterpret_cast<const float4*>(src + c);
    float4 d = *reinterpret_cast<const float4*>(src + c + 4);
    uint4 r;
    r.x = cvt_pk_bf16(a.x*sc, a.y*sc);
    r.y = cvt_pk_bf16(a.z*sc, a.w*sc);
    r.z = cvt_pk_bf16(d.x*sc, d.y*sc);
    r.w = cvt_pk_bf16(d.z*sc, d.w*sc);
    *reinterpret_cast<uint4*>(Wbf + (size_t)o*NC + c) = r;
}

// ---------------- Kernel A: fused QKV projection ----------------------------
__global__ __launch_bounds__(256, 2) void qkv_proj(
    const float* __restrict__ x,
    const unsigned short* __restrict__ Wbf,
    const float* __restrict__ bq, const float* __restrict__ bk,
    const float* __restrict__ bv,
    unsigned short* __restrict__ QT, unsigned short* __restrict__ KT,
    unsigned char* __restrict__ V)
{
    const int nblk = blockIdx.x;
    const int b    = blockIdx.y;
    const int t = threadIdx.x;
    const int wid = t >> 6;
    const int l = t & 63;
    const int lg = l >> 4, lr = l & 15;
    const int n0 = nblk * 64;
    const float* xb = x + (size_t)b * NC * NN;

    __shared__ unsigned short XT[2][64][72];

    const int o_base = wid * 160;

    f32x4 acc[10][4];
    #pragma unroll
    for (int mt = 0; mt < 10; ++mt) {
        const int ob = o_base + mt*16;
        #pragma unroll
        for (int bb = 0; bb < 4; ++bb) {
            const int o = ob + lg*4 + bb;
            float bias = (ob < 64) ? bq[o]*LOG2E : (ob < 128) ? bk[o-64] : bv[o-128];
            #pragma unroll
            for (int nt = 0; nt < 4; ++nt) acc[mt][nt][bb] = bias;
        }
    }

    const int cq = (t >> 4) << 2;
    const int n4 = (t & 15) << 2;
    float4 xs0, xs1, xs2, xs3;
    auto xload = [&](int ks) {
        const float* xr = xb + (size_t)(ks*64 + cq)*NN + n0 + n4;
        xs0 = *reinterpret_cast<const float4*>(xr);
        xs1 = *reinterpret_cast<const float4*>(xr + NN);
        xs2 = *reinterpret_cast<const float4*>(xr + 2*(size_t)NN);
        xs3 = *reinterpret_cast<const float4*>(xr + 3*(size_t)NN);
    };
    auto xwrite = [&](int buf) {
        uint2 w;
        w.x = cvt_pk_bf16(xs0.x, xs1.x); w.y = cvt_pk_bf16(xs2.x, xs3.x);
        *reinterpret_cast<uint2*>(&XT[buf][n4+0][cq]) = w;
        w.x = cvt_pk_bf16(xs0.y, xs1.y); w.y = cvt_pk_bf16(xs2.y, xs3.y);
        *reinterpret_cast<uint2*>(&XT[buf][n4+1][cq]) = w;
        w.x = cvt_pk_bf16(xs0.z, xs1.z); w.y = cvt_pk_bf16(xs2.z, xs3.z);
        *reinterpret_cast<uint2*>(&XT[buf][n4+2][cq]) = w;
        w.x = cvt_pk_bf16(xs0.w, xs1.w); w.y = cvt_pk_bf16(xs2.w, xs3.w);
        *reinterpret_cast<uint2*>(&XT[buf][n4+3][cq]) = w;
    };

    xload(0);
    xwrite(0);
    __syncthreads();

    for (int ks = 0; ks < 8; ++ks) {
        const int buf = ks & 1;
        const int c0 = ks * 64;
        if (ks < 7) xload(ks + 1);
        #pragma unroll
        for (int k2 = 0; k2 < 2; ++k2) {
            short8 bf[4];
            #pragma unroll
            for (int nt = 0; nt < 4; ++nt)
                bf[nt] = *reinterpret_cast<const short8*>(&XT[buf][nt*16 + lr][k2*32 + lg*8]);
            #pragma unroll
            for (int mt = 0; mt < 10; ++mt) {
                short8 af = *reinterpret_cast<const short8*>(
                    Wbf + (size_t)(o_base + mt*16 + lr)*NC + c0 + k2*32 + lg*8);
                #pragma unroll
                for (int nt = 0; nt < 4; ++nt)
                    acc[mt][nt] = __builtin_amdgcn_mfma_f32_16x16x32_bf16(af, bf[nt], acc[mt][nt], 0, 0, 0);
            }
        }
        if (ks < 7) xwrite(buf ^ 1);
        __syncthreads();
    }

    #pragma unroll
    for (int mt = 0; mt < 10; ++mt) {
        const int ob = o_base + mt*16;
        const int ol = ob + lg*4;
        #pragma unroll
        for (int nt = 0; nt < 4; ++nt) {
            const int n = n0 + nt*16 + lr;
            if (ob < 128) {
                uint2 pk;
                pk.x = cvt_pk_bf16(acc[mt][nt][0], acc[mt][nt][1]);
                pk.y = cvt_pk_bf16(acc[mt][nt][2], acc[mt][nt][3]);
                unsigned short* dst = (ob < 64) ? (QT + ((size_t)b*NN + n)*ND + ol)
                                                : (KT + ((size_t)b*NN + n)*ND + (ol - 64));
                *reinterpret_cast<uint2*>(dst) = pk;
            } else {
                const int c = ol - 128;
                #pragma unroll
                for (int bb = 0; bb < 4; ++bb) {
                    int v8 = __builtin_amdgcn_cvt_pk_fp8_f32(acc[mt][nt][bb], 0.f, 0, false);
                    V[((size_t)b*NC + c + bb)*NN + n] = (unsigned char)(v8 & 0xff);
                }
            }
        }
    }
}

// ---------------- Kernel S: pass-1 row-max, s-split halves ------------------
// 256 blocks x 1024 thr (16 waves, M=256 rows, 2048 keys per block).
// Max-only (order-free). LDS K dbuf, 1 lgkm barrier/tile. Fragment layout
// identical to attn's QKt => MFMA determinism gives bitwise-equal S in pass-2.
__global__ __launch_bounds__(1024) void stats(
    const unsigned short* __restrict__ QT,
    const unsigned short* __restrict__ KT,
    float* __restrict__ Mh)   // [2][NB*NN]
{
    const int bi = blockIdx.x;
    const int b    = bi & 7;
    const int nt   = (bi >> 3) & 15;
    const int half = bi >> 7;
    const int n0 = nt * 256;
    const int t = threadIdx.x;
    const int wid = t >> 6;           // 0..15
    const int l = t & 63;
    const int lg = l >> 4, lr = l & 15;

    __shared__ __align__(16) unsigned short Klds[2*64*64];   // 16 KB dbuf

    const unsigned short* Qb = QT + ((size_t)b*NN + n0)*ND;
    const unsigned short* Kb = KT + (size_t)b*NN*ND + (size_t)half*2048*ND;

    short8 qf0 = *reinterpret_cast<const short8*>(Qb + (size_t)(16*wid + lr)*ND + lg*8);
    short8 qf1 = *reinterpret_cast<const short8*>(Qb + (size_t)(16*wid + lr)*ND + 32 + lg*8);

    const int krow = t >> 3;
    const int kdst = krow*64 + ((8*(t & 7)) ^ (8*(krow & 7)));
    if (t < 512) {
        short8 k0 = *reinterpret_cast<const short8*>(Kb + (size_t)t*8);
        *reinterpret_cast<short8*>(&Klds[kdst]) = k0;
    }

    const int kswz = 8*(lr & 7);
    f32x4 mr = f32x4{-1e30f, -1e30f, -1e30f, -1e30f};

    barrier_lgkm();

    for (int i = 0; i < 32; ++i) {
        short8 kr;
        if (t < 512 && i < 31)
            kr = *reinterpret_cast<const short8*>(Kb + (size_t)(i+1)*4096 + t*8);

        const unsigned short* kbuf = &Klds[(i & 1)*4096];
        #pragma unroll
        for (int j = 0; j < 4; ++j) {
            const unsigned short* kp = kbuf + (16*j + lr)*64;
            short8 a0 = *reinterpret_cast<const short8*>(kp + ((8*lg) ^ kswz));
            short8 a1 = *reinterpret_cast<const short8*>(kp + ((32 + 8*lg) ^ kswz));
            f32x4 acc = __builtin_amdgcn_mfma_f32_16x16x32_bf16(a0, qf0, f32x4{0.f,0.f,0.f,0.f}, 0, 0, 0);
            acc = __builtin_amdgcn_mfma_f32_16x16x32_bf16(a1, qf1, acc, 0, 0, 0);
            mr[0] = fmaxf(mr[0], acc[0]);
            mr[1] = fmaxf(mr[1], acc[1]);
            mr[2] = fmaxf(mr[2], acc[2]);
            mr[3] = fmaxf(mr[3], acc[3]);
        }
        if (t < 512 && i < 31)
            *reinterpret_cast<short8*>(&Klds[((i+1) & 1)*4096 + kdst]) = kr;
        barrier_lgkm();
    }

    float mx = fmaxf(fmaxf(mr[0], mr[1]), fmaxf(mr[2], mr[3]));
    mx = fmaxf(mx, __shfl_xor(mx, 16));
    mx = fmaxf(mx, __shfl_xor(mx, 32));
    if (lg == 0) Mh[(size_t)half*NB*NN + (size_t)b*NN + n0 + 16*wid + lr] = mx;
}

// ---------------- Kernel B: pass-2 — lag-2 ring, P=exp2(S-M), PV, residual --
// M=128 q/block, 8 waves, KVBLK=64, ONE barrier per TWO tiles (4-slot K/P
// rings). No softmax stats in-loop except per-lane L adds. M from pass-1.
__global__ __launch_bounds__(512, 2) void attn(
    const unsigned short* __restrict__ QT,
    const unsigned short* __restrict__ KT,
    const unsigned char* __restrict__ V,
    const float* __restrict__ Mh,
    const float* __restrict__ x,
    const float* __restrict__ alpha_p,
    float* __restrict__ out)
{
    const int bi = blockIdx.x;
    const int b  = bi & 7;            // batch per XCD (L2 locality)
    const int n0 = (bi >> 3) * 128;
    const int t = threadIdx.x;
    const int wid = t >> 6;
    const int l = t & 63;
    const int lg = l >> 4, lr = l & 15;

    __shared__ __align__(16) unsigned short Klds[4*64*64];    // 32 KB ring
    __shared__ __align__(16) unsigned char  Plds[4*128*128];  // 64 KB ring
    __shared__ float Ll[128];

    const unsigned short* Qb = QT + ((size_t)b*NN + n0)*ND;
    const unsigned short* Kb = KT + (size_t)b*NN*ND;
    const unsigned char*  Vb = V + ((size_t)b*NC + 64*wid)*NN;

    short8 qf0 = *reinterpret_cast<const short8*>(Qb + (size_t)(16*wid + lr)*ND + lg*8);
    short8 qf1 = *reinterpret_cast<const short8*>(Qb + (size_t)(16*wid + lr)*ND + 32 + lg*8);

    const int nrow = n0 + 16*wid + lr;
    const float Mreg = fmaxf(Mh[(size_t)b*NN + nrow], Mh[(size_t)NB*NN + (size_t)b*NN + nrow]);

    const int krow = t >> 3;
    const int kdst = krow*64 + ((8*(t & 7)) ^ (8*(krow & 7)));

    {   // stage K(0) -> slot0, K(1) -> slot1
        short8 k0 = *reinterpret_cast<const short8*>(Kb + (size_t)t*8);
        short8 k1 = *reinterpret_cast<const short8*>(Kb + 4096 + (size_t)t*8);
        *reinterpret_cast<short8*>(&Klds[kdst]) = k0;
        *reinterpret_cast<short8*>(&Klds[4096 + kdst]) = k1;
    }

    f32x4 oacc[8][4];
    #pragma unroll
    for (int mt = 0; mt < 8; ++mt)
        #pragma unroll
        for (int ct = 0; ct < 4; ++ct)
            oacc[mt][ct] = f32x4{0.f, 0.f, 0.f, 0.f};

    float lrun = 0.f;

    long vf[4];
    #pragma unroll
    for (int ct = 0; ct < 4; ++ct)
        vf[ct] = *reinterpret_cast<const long*>(Vb + (size_t)(ct*16 + lr)*NN + 8*lg);

    barrier_lgkm();   // K(0), K(1) visible

    const int kswz = 8*(lr & 7);
    const int pswz = 8*lr;
    const int prow = (16*wid + lr) * 128;

    auto PVstep = [&](const unsigned char* pbase, int k2, int s_pref) {
        long vfn[4];
        #pragma unroll
        for (int ct = 0; ct < 4; ++ct)
            vfn[ct] = *reinterpret_cast<const long*>(
                Vb + (size_t)(ct*16 + lr)*NN + s_pref + 8*lg);
        long pf[8];
        #pragma unroll
        for (int mt = 0; mt < 8; ++mt)
            pf[mt] = *reinterpret_cast<const long*>(
                pbase + (16*mt + lr)*128 + ((k2*32 + 8*lg) ^ pswz));
        __builtin_amdgcn_s_setprio(1);
        #pragma unroll
        for (int mt = 0; mt < 8; ++mt)
            #pragma unroll
            for (int ct = 0; ct < 4; ++ct)
                oacc[mt][ct] = __builtin_amdgcn_mfma_f32_16x16x32_fp8_fp8(
                    pf[mt], vf[ct], oacc[mt][ct], 0, 0, 0);
        __builtin_amdgcn_s_setprio(0);
        #pragma unroll
        for (int ct = 0; ct < 4; ++ct) vf[ct] = vfn[ct];
    };

    auto QKt = [&](const unsigned short* kbuf, f32x4 (&sn)[4]) {
        #pragma unroll
        for (int st8 = 0; st8 < 4; ++st8) {
            const unsigned short* kp = kbuf + (16*st8 + lr)*64;
            short8 a0 = *reinterpret_cast<const short8*>(kp + ((8*lg) ^ kswz));
            short8 a1 = *reinterpret_cast<const short8*>(kp + ((32 + 8*lg) ^ kswz));
            sn[st8] = __builtin_amdgcn_mfma_f32_16x16x32_bf16(a0, qf0, f32x4{0.f,0.f,0.f,0.f}, 0, 0, 0);
            sn[st8] = __builtin_amdgcn_mfma_f32_16x16x32_bf16(a1, qf1, sn[st8], 0, 0, 0);
        }
    };

    // exp + fp8-pack + LDS write + per-lane L adds (no stats chain)
    auto EXPK = [&](const f32x4 (&sn)[4], unsigned char* pb) {
        #pragma unroll
        for (int st8 = 0; st8 < 4; ++st8) {
            float p0 = __builtin_amdgcn_exp2f(sn[st8][0] - Mreg);
            float p1 = __builtin_amdgcn_exp2f(sn[st8][1] - Mreg);
            float p2 = __builtin_amdgcn_exp2f(sn[st8][2] - Mreg);
            float p3 = __builtin_amdgcn_exp2f(sn[st8][3] - Mreg);
            lrun += (p0 + p1) + (p2 + p3);
            int d = __builtin_amdgcn_cvt_pk_fp8_f32(p0, p1, 0, false);
            d = __builtin_amdgcn_cvt_pk_fp8_f32(p2, p3, d, true);
            *reinterpret_cast<int*>(&pb[prow + ((16*st8 + 4*lg) ^ pswz)]) = d;
        }
    };

    // ---- prologue: P(0)->slot0, P(1)->slot1; stage K(2)->slot2, K(3)->slot3
    {
        f32x4 sn[4];
        QKt(&Klds[0], sn);
        short8 k2r = *reinterpret_cast<const short8*>(Kb + 2*(size_t)4096 + t*8);
        EXPK(sn, Plds);
        QKt(&Klds[4096], sn);
        short8 k3r = *reinterpret_cast<const short8*>(Kb + 3*(size_t)4096 + t*8);
        EXPK(sn, Plds + 16384);
        *reinterpret_cast<short8*>(&Klds[2*4096 + kdst]) = k2r;
        *reinterpret_cast<short8*>(&Klds[3*4096 + kdst]) = k3r;
    }
    barrier_lgkm();   // P(0),P(1),K(2),K(3) visible

    // ---- main loop: 2 tiles per barrier (31 segments, i = 0..60 step 2) ----
    for (int i = 0; i < 62; i += 2) {
        const int s0a = i * 64;
        const int s0b = s0a + 64;
        const int i4 = (i + 4 < 64) ? i + 4 : 63;
        const int i5 = (i + 5 < 64) ? i + 5 : 63;
        const unsigned char* pA = Plds + (size_t)(i & 3)*16384;
        const unsigned char* pB = Plds + (size_t)((i + 1) & 3)*16384;

        // --- first tile of segment ---
        short8 kra = *reinterpret_cast<const short8*>(Kb + (size_t)i4*4096 + t*8);
        f32x4 sn[4];
        QKt(&Klds[((i + 2) & 3)*4096], sn);          // QK^T(i+2)
        PVstep(pA, 0, s0a + 32);                      // PV(i) k2=0
        EXPK(sn, Plds + (size_t)((i + 2) & 3)*16384); // P(i+2) (slot not read this seg)
        PVstep(pA, 1, s0a + 64);                      // PV(i) k2=1
        *reinterpret_cast<short8*>(&Klds[(i & 3)*4096 + kdst]) = kra;   // K(i+4)

        // --- second tile of segment ---
        short8 krb = *reinterpret_cast<const short8*>(Kb + (size_t)i5*4096 + t*8);
        QKt(&Klds[((i + 3) & 3)*4096], sn);           // QK^T(i+3)
        PVstep(pB, 0, s0b + 32);                      // PV(i+1) k2=0
        EXPK(sn, Plds + (size_t)((i + 3) & 3)*16384); // P(i+3)
        PVstep(pB, 1, s0b + 64);                      // PV(i+1) k2=1; pref V(i+2)
        *reinterpret_cast<short8*>(&Klds[((i + 1) & 3)*4096 + kdst]) = krb; // K(i+5)

        barrier_lgkm();   // LDS-only drain: V prefetches stay in flight
    }

    // ---- tail: PV(62), PV(63) ----
    {
        const unsigned char* pA = Plds + (size_t)(62 & 3)*16384;
        const unsigned char* pB = Plds + (size_t)(63 & 3)*16384;
        const int s0a = 62 * 64;
        PVstep(pA, 0, s0a + 32);
        PVstep(pA, 1, s0a + 64);
        PVstep(pB, 0, s0a + 96);
        PVstep(pB, 1, s0a);        // dummy prefetch
    }

    // ---- finalize L: cross-lane reduce once; share via LDS ----
    lrun += __shfl_xor(lrun, 16);
    lrun += __shfl_xor(lrun, 32);
    if (lg == 0) Ll[16*wid + lr] = lrun;
    __syncthreads();

    const float alpha = alpha_p[0];
    #pragma unroll
    for (int mt = 0; mt < 8; ++mt) {
        float4 l4 = *reinterpret_cast<const float4*>(&Ll[16*mt + 4*lg]);
        float ar0 = alpha / l4.x, ar1 = alpha / l4.y, ar2 = alpha / l4.z, ar3 = alpha / l4.w;
        #pragma unroll
        for (int ct = 0; ct < 4; ++ct) {
            const int c = 64*wid + 16*ct + lr;
            const size_t base = ((size_t)b*NC + c)*NN + n0 + 16*mt + 4*lg;
            float4 x4 = *reinterpret_cast<const float4*>(x + base);
            float4 o4;
            o4.x = oacc[mt][ct][0] * ar0 + x4.x;
            o4.y = oacc[mt][ct][1] * ar1 + x4.y;
            o4.z = oacc[mt][ct][2] * ar2 + x4.z;
            o4.w = oacc[mt][ct][3] * ar3 + x4.w;
            *reinterpret_cast<float4*>(out + base) = o4;
        }
    }
}

extern "C" void kernel_launch(void* const* d_in, const int* in_sizes, int n_in,
                              void* d_out, int out_size, void* d_ws, size_t ws_size,
                              hipStream_t stream) {
    const float* x     = (const float*)d_in[0];
    const float* wq    = (const float*)d_in[1];
    const float* bq    = (const float*)d_in[2];
    const float* wk    = (const float*)d_in[3];
    const float* bk    = (const float*)d_in[4];
    const float* wv    = (const float*)d_in[5];
    const float* bv    = (const float*)d_in[6];
    const float* alpha = (const float*)d_in[7];

    // ws: QT bf16 4MB | KT bf16 4MB | V fp8 16MB | Wbf 640KB | Mh 2x128KB
    unsigned short* QT = (unsigned short*)d_ws;
    unsigned short* KT = QT + (size_t)NB*NN*ND;
    unsigned char*  V  = (unsigned char*)(KT + (size_t)NB*NN*ND);
    unsigned short* Wbf = (unsigned short*)(V + (size_t)NB*NC*NN);
    float* Mh = (float*)(Wbf + (size_t)640*NC);

    wprep<<<160, 256, 0, stream>>>(wq, wk, wv, Wbf);
    dim3 gA(64, 8);
    qkv_proj<<<gA, 256, 0, stream>>>(x, Wbf, bq, bk, bv, QT, KT, V);
    stats<<<256, 1024, 0, stream>>>(QT, KT, Mh);
    attn<<<NB * (NN/128), 512, 0, stream>>>(QT, KT, V, Mh, x, alpha, (float*)d_out);
}

// Round 14
// 209.964 us; speedup vs baseline: 1.8710x; 1.0599x over previous
//
#include <hip/hip_runtime.h>
#include <hip/hip_bf16.h>
#include <stdint.h>

#define NB 8
#define NC 512
#define NN 4096
#define ND 64

typedef __attribute__((ext_vector_type(8))) short short8;
typedef __attribute__((ext_vector_type(4))) float f32x4;
typedef __attribute__((ext_vector_type(8))) int i32x8;

#define LOG2E 1.44269504088896340736f

static __device__ __forceinline__ uint32_t cvt_pk_bf16(float lo, float hi) {
    uint32_t r;
    asm("v_cvt_pk_bf16_f32 %0, %1, %2" : "=v"(r) : "v"(lo), "v"(hi));
    return r;
}

// barrier that drains LDS ops only — global loads stay in flight (T4)
static __device__ __forceinline__ void barrier_lgkm() {
    asm volatile("s_waitcnt lgkmcnt(0)" ::: "memory");
    __builtin_amdgcn_s_barrier();
    __builtin_amdgcn_sched_barrier(0);
}

// ---------------- Kernel 0: W fp32 -> bf16 (LOG2E baked into q rows) --------
__global__ __launch_bounds__(256) void wprep(
    const float* __restrict__ wq, const float* __restrict__ wk,
    const float* __restrict__ wv, unsigned short* __restrict__ Wbf)
{
    const int g = blockIdx.x * 256 + threadIdx.x;
    const int o = g >> 6;
    const int c = (g & 63) << 3;
    const float* src; float sc;
    if (o < 64)       { src = wq + (size_t)o*NC;        sc = LOG2E; }
    else if (o < 128) { src = wk + (size_t)(o-64)*NC;   sc = 1.f; }
    else              { src = wv + (size_t)(o-128)*NC;  sc = 1.f; }
    float4 a = *reinterpret_cast<const float4*>(src + c);
    float4 d = *reinterpret_cast<const float4*>(src + c + 4);
    uint4 r;
    r.x = cvt_pk_bf16(a.x*sc, a.y*sc);
    r.y = cvt_pk_bf16(a.z*sc, a.w*sc);
    r.z = cvt_pk_bf16(d.x*sc, d.y*sc);
    r.w = cvt_pk_bf16(d.z*sc, d.w*sc);
    *reinterpret_cast<uint4*>(Wbf + (size_t)o*NC + c) = r;
}

// ---------------- Kernel A: fused QKV projection ----------------------------
__global__ __launch_bounds__(256, 2) void qkv_proj(
    const float* __restrict__ x,
    const unsigned short* __restrict__ Wbf,
    const float* __restrict__ bq, const float* __restrict__ bk,
    const float* __restrict__ bv,
    unsigned short* __restrict__ QT, unsigned short* __restrict__ KT,
    unsigned char* __restrict__ V)
{
    const int nblk = blockIdx.x;
    const int b    = blockIdx.y;
    const int t = threadIdx.x;
    const int wid = t >> 6;
    const int l = t & 63;
    const int lg = l >> 4, lr = l & 15;
    const int n0 = nblk * 64;
    const float* xb = x + (size_t)b * NC * NN;

    __shared__ unsigned short XT[2][64][72];

    const int o_base = wid * 160;

    f32x4 acc[10][4];
    #pragma unroll
    for (int mt = 0; mt < 10; ++mt) {
        const int ob = o_base + mt*16;
        #pragma unroll
        for (int bb = 0; bb < 4; ++bb) {
            const int o = ob + lg*4 + bb;
            float bias = (ob < 64) ? bq[o]*LOG2E : (ob < 128) ? bk[o-64] : bv[o-128];
            #pragma unroll
            for (int nt = 0; nt < 4; ++nt) acc[mt][nt][bb] = bias;
        }
    }

    const int cq = (t >> 4) << 2;
    const int n4 = (t & 15) << 2;
    float4 xs0, xs1, xs2, xs3;
    auto xload = [&](int ks) {
        const float* xr = xb + (size_t)(ks*64 + cq)*NN + n0 + n4;
        xs0 = *reinterpret_cast<const float4*>(xr);
        xs1 = *reinterpret_cast<const float4*>(xr + NN);
        xs2 = *reinterpret_cast<const float4*>(xr + 2*(size_t)NN);
        xs3 = *reinterpret_cast<const float4*>(xr + 3*(size_t)NN);
    };
    auto xwrite = [&](int buf) {
        uint2 w;
        w.x = cvt_pk_bf16(xs0.x, xs1.x); w.y = cvt_pk_bf16(xs2.x, xs3.x);
        *reinterpret_cast<uint2*>(&XT[buf][n4+0][cq]) = w;
        w.x = cvt_pk_bf16(xs0.y, xs1.y); w.y = cvt_pk_bf16(xs2.y, xs3.y);
        *reinterpret_cast<uint2*>(&XT[buf][n4+1][cq]) = w;
        w.x = cvt_pk_bf16(xs0.z, xs1.z); w.y = cvt_pk_bf16(xs2.z, xs3.z);
        *reinterpret_cast<uint2*>(&XT[buf][n4+2][cq]) = w;
        w.x = cvt_pk_bf16(xs0.w, xs1.w); w.y = cvt_pk_bf16(xs2.w, xs3.w);
        *reinterpret_cast<uint2*>(&XT[buf][n4+3][cq]) = w;
    };

    xload(0);
    xwrite(0);
    __syncthreads();

    for (int ks = 0; ks < 8; ++ks) {
        const int buf = ks & 1;
        const int c0 = ks * 64;
        if (ks < 7) xload(ks + 1);
        #pragma unroll
        for (int k2 = 0; k2 < 2; ++k2) {
            short8 bf[4];
            #pragma unroll
            for (int nt = 0; nt < 4; ++nt)
                bf[nt] = *reinterpret_cast<const short8*>(&XT[buf][nt*16 + lr][k2*32 + lg*8]);
            #pragma unroll
            for (int mt = 0; mt < 10; ++mt) {
                short8 af = *reinterpret_cast<const short8*>(
                    Wbf + (size_t)(o_base + mt*16 + lr)*NC + c0 + k2*32 + lg*8);
                #pragma unroll
                for (int nt = 0; nt < 4; ++nt)
                    acc[mt][nt] = __builtin_amdgcn_mfma_f32_16x16x32_bf16(af, bf[nt], acc[mt][nt], 0, 0, 0);
            }
        }
        if (ks < 7) xwrite(buf ^ 1);
        __syncthreads();
    }

    #pragma unroll
    for (int mt = 0; mt < 10; ++mt) {
        const int ob = o_base + mt*16;
        const int ol = ob + lg*4;
        #pragma unroll
        for (int nt = 0; nt < 4; ++nt) {
            const int n = n0 + nt*16 + lr;
            if (ob < 128) {
                uint2 pk;
                pk.x = cvt_pk_bf16(acc[mt][nt][0], acc[mt][nt][1]);
                pk.y = cvt_pk_bf16(acc[mt][nt][2], acc[mt][nt][3]);
                unsigned short* dst = (ob < 64) ? (QT + ((size_t)b*NN + n)*ND + ol)
                                                : (KT + ((size_t)b*NN + n)*ND + (ol - 64));
                *reinterpret_cast<uint2*>(dst) = pk;
            } else {
                const int c = ol - 128;
                #pragma unroll
                for (int bb = 0; bb < 4; ++bb) {
                    int v8 = __builtin_amdgcn_cvt_pk_fp8_f32(acc[mt][nt][bb], 0.f, 0, false);
                    V[((size_t)b*NC + c + bb)*NN + n] = (unsigned char)(v8 & 0xff);
                }
            }
        }
    }
}

// ---------------- Kernel S: pass-1 row-max, s-split halves ------------------
__global__ __launch_bounds__(1024) void stats(
    const unsigned short* __restrict__ QT,
    const unsigned short* __restrict__ KT,
    float* __restrict__ Mh)   // [2][NB*NN]
{
    const int bi = blockIdx.x;
    const int b    = bi & 7;
    const int nt   = (bi >> 3) & 15;
    const int half = bi >> 7;
    const int n0 = nt * 256;
    const int t = threadIdx.x;
    const int wid = t >> 6;
    const int l = t & 63;
    const int lg = l >> 4, lr = l & 15;

    __shared__ __align__(16) unsigned short Klds[2*64*64];

    const unsigned short* Qb = QT + ((size_t)b*NN + n0)*ND;
    const unsigned short* Kb = KT + (size_t)b*NN*ND + (size_t)half*2048*ND;

    short8 qf0 = *reinterpret_cast<const short8*>(Qb + (size_t)(16*wid + lr)*ND + lg*8);
    short8 qf1 = *reinterpret_cast<const short8*>(Qb + (size_t)(16*wid + lr)*ND + 32 + lg*8);

    const int krow = t >> 3;
    const int kdst = krow*64 + ((8*(t & 7)) ^ (8*(krow & 7)));
    if (t < 512) {
        short8 k0 = *reinterpret_cast<const short8*>(Kb + (size_t)t*8);
        *reinterpret_cast<short8*>(&Klds[kdst]) = k0;
    }

    const int kswz = 8*(lr & 7);
    f32x4 mr = f32x4{-1e30f, -1e30f, -1e30f, -1e30f};

    barrier_lgkm();

    for (int i = 0; i < 32; ++i) {
        short8 kr;
        if (t < 512 && i < 31)
            kr = *reinterpret_cast<const short8*>(Kb + (size_t)(i+1)*4096 + t*8);

        const unsigned short* kbuf = &Klds[(i & 1)*4096];
        #pragma unroll
        for (int j = 0; j < 4; ++j) {
            const unsigned short* kp = kbuf + (16*j + lr)*64;
            short8 a0 = *reinterpret_cast<const short8*>(kp + ((8*lg) ^ kswz));
            short8 a1 = *reinterpret_cast<const short8*>(kp + ((32 + 8*lg) ^ kswz));
            f32x4 acc = __builtin_amdgcn_mfma_f32_16x16x32_bf16(a0, qf0, f32x4{0.f,0.f,0.f,0.f}, 0, 0, 0);
            acc = __builtin_amdgcn_mfma_f32_16x16x32_bf16(a1, qf1, acc, 0, 0, 0);
            mr[0] = fmaxf(mr[0], acc[0]);
            mr[1] = fmaxf(mr[1], acc[1]);
            mr[2] = fmaxf(mr[2], acc[2]);
            mr[3] = fmaxf(mr[3], acc[3]);
        }
        if (t < 512 && i < 31)
            *reinterpret_cast<short8*>(&Klds[((i+1) & 1)*4096 + kdst]) = kr;
        barrier_lgkm();
    }

    float mx = fmaxf(fmaxf(mr[0], mr[1]), fmaxf(mr[2], mr[3]));
    mx = fmaxf(mx, __shfl_xor(mx, 16));
    mx = fmaxf(mx, __shfl_xor(mx, 32));
    if (lg == 0) Mh[(size_t)half*NB*NN + (size_t)b*NN + n0 + 16*wid + lr] = mx;
}

// ---------------- Kernel B: pass-2 — K=128 MX-fp8 MFMA PV (scale=1.0) -------
// M=128 q/block, 8 waves, KVBLK=128 (32 tiles), lag-1 dbuf, 1 barrier/tile.
// PV: __builtin_amdgcn_mfma_scale_f32_16x16x128_f8f6f4 with E8M0 scale 0x7F
// (=2^0). V loaded inside PV per ct-pair (register diet); K issue-early after
// EXPK (hides under PV). M from pass-1; L accumulated per-lane in EXPK.
__global__ __launch_bounds__(512, 2) void attn(
    const unsigned short* __restrict__ QT,
    const unsigned short* __restrict__ KT,
    const unsigned char* __restrict__ V,
    const float* __restrict__ Mh,
    const float* __restrict__ x,
    const float* __restrict__ alpha_p,
    float* __restrict__ out)
{
    const int bi = blockIdx.x;
    const int b  = bi & 7;            // batch per XCD (L2 locality)
    const int n0 = (bi >> 3) * 128;
    const int t = threadIdx.x;
    const int wid = t >> 6;
    const int l = t & 63;
    const int lg = l >> 4, lr = l & 15;

    __shared__ __align__(16) unsigned short Klds[2*128*64];   // 32 KB dbuf
    __shared__ __align__(16) unsigned char  Plds[2*128*128];  // 32 KB dbuf
    __shared__ float Ll[128];

    const unsigned short* Qb = QT + ((size_t)b*NN + n0)*ND;
    const unsigned short* Kb = KT + (size_t)b*NN*ND;
    const unsigned char*  Vb = V + ((size_t)b*NC + 64*wid)*NN;

    short8 qf0 = *reinterpret_cast<const short8*>(Qb + (size_t)(16*wid + lr)*ND + lg*8);
    short8 qf1 = *reinterpret_cast<const short8*>(Qb + (size_t)(16*wid + lr)*ND + 32 + lg*8);

    const int nrow = n0 + 16*wid + lr;
    const float Mreg = fmaxf(Mh[(size_t)b*NN + nrow], Mh[(size_t)NB*NN + (size_t)b*NN + nrow]);

    // K staging: 128x64 bf16 tile = 16 KB; thread copies chunks t and t+512
    const int kr0_row = t >> 3;
    const int kr1_row = 64 + (t >> 3);
    const int kc0 = kr0_row*64 + ((8*(t & 7)) ^ (8*(kr0_row & 7)));
    const int kc1 = kr1_row*64 + ((8*(t & 7)) ^ (8*(kr1_row & 7)));

    {   // stage K(0) -> slot0
        short8 a = *reinterpret_cast<const short8*>(Kb + (size_t)t*8);
        short8 c = *reinterpret_cast<const short8*>(Kb + 4096 + (size_t)t*8);
        *reinterpret_cast<short8*>(&Klds[kc0]) = a;
        *reinterpret_cast<short8*>(&Klds[kc1]) = c;
    }

    f32x4 oacc[8][4];
    #pragma unroll
    for (int mt = 0; mt < 8; ++mt)
        #pragma unroll
        for (int ct = 0; ct < 4; ++ct)
            oacc[mt][ct] = f32x4{0.f, 0.f, 0.f, 0.f};

    float lrun = 0.f;

    barrier_lgkm();   // K(0) visible

    const int kswz = 8*(lr & 7);
    const int pswz = 8*lr;
    const int prow = (16*wid + lr) * 128;

    // QK^T half h of tile (rows 64h..64h+63): sn[j] = S^T[s=64h+16j+4lg+bb][m]
    auto QKt = [&](const unsigned short* kbuf, int h, f32x4 (&sn)[4]) {
        #pragma unroll
        for (int j = 0; j < 4; ++j) {
            const unsigned short* kp = kbuf + (64*h + 16*j + lr)*64;
            short8 a0 = *reinterpret_cast<const short8*>(kp + ((8*lg) ^ kswz));
            short8 a1 = *reinterpret_cast<const short8*>(kp + ((32 + 8*lg) ^ kswz));
            sn[j] = __builtin_amdgcn_mfma_f32_16x16x32_bf16(a0, qf0, f32x4{0.f,0.f,0.f,0.f}, 0, 0, 0);
            sn[j] = __builtin_amdgcn_mfma_f32_16x16x32_bf16(a1, qf1, sn[j], 0, 0, 0);
        }
    };

    // exp + fp8-pack + LDS write + per-lane L adds, for half h
    auto EXPK = [&](const f32x4 (&sn)[4], int h, unsigned char* pb) {
        #pragma unroll
        for (int j = 0; j < 4; ++j) {
            float p0 = __builtin_amdgcn_exp2f(sn[j][0] - Mreg);
            float p1 = __builtin_amdgcn_exp2f(sn[j][1] - Mreg);
            float p2 = __builtin_amdgcn_exp2f(sn[j][2] - Mreg);
            float p3 = __builtin_amdgcn_exp2f(sn[j][3] - Mreg);
            lrun += (p0 + p1) + (p2 + p3);
            int d = __builtin_amdgcn_cvt_pk_fp8_f32(p0, p1, 0, false);
            d = __builtin_amdgcn_cvt_pk_fp8_f32(p2, p3, d, true);
            *reinterpret_cast<int*>(&pb[prow + ((64*h + 16*j + 4*lg) ^ pswz)]) = d;
        }
    };

    // one V B-fragment: V[c = 16*ct + 64*wid + lr][s0 + 32*lg .. +31]
    auto VLD1 = [&](int ct, int s0) -> i32x8 {
        const uint4* vp = reinterpret_cast<const uint4*>(
            Vb + (size_t)(ct*16 + lr)*NN + s0 + 32*lg);
        uint4 lo = vp[0], hi = vp[1];
        i32x8 v;
        v[0] = lo.x; v[1] = lo.y; v[2] = lo.z; v[3] = lo.w;
        v[4] = hi.x; v[5] = hi.y; v[6] = hi.z; v[7] = hi.w;
        return v;
    };

    // PV for one 128-key tile: 8 mt x 4 ct, one K=128 MFMA each
    auto PV = [&](const unsigned char* pcur, int s0) {
        #pragma unroll
        for (int h = 0; h < 2; ++h) {
            i32x8 v0 = VLD1(2*h, s0);
            i32x8 v1 = VLD1(2*h + 1, s0);
            __builtin_amdgcn_s_setprio(1);
            #pragma unroll
            for (int mt = 0; mt < 8; ++mt) {
                const unsigned char* pr = pcur + (16*mt + lr)*128;
                int2 q0 = *reinterpret_cast<const int2*>(pr + ((32*lg +  0) ^ pswz));
                int2 q1 = *reinterpret_cast<const int2*>(pr + ((32*lg +  8) ^ pswz));
                int2 q2 = *reinterpret_cast<const int2*>(pr + ((32*lg + 16) ^ pswz));
                int2 q3 = *reinterpret_cast<const int2*>(pr + ((32*lg + 24) ^ pswz));
                i32x8 pf;
                pf[0] = q0.x; pf[1] = q0.y; pf[2] = q1.x; pf[3] = q1.y;
                pf[4] = q2.x; pf[5] = q2.y; pf[6] = q3.x; pf[7] = q3.y;
                oacc[mt][2*h] = __builtin_amdgcn_mfma_scale_f32_16x16x128_f8f6f4(
                    pf, v0, oacc[mt][2*h], 0, 0, 0, 127, 0, 127);
                oacc[mt][2*h + 1] = __builtin_amdgcn_mfma_scale_f32_16x16x128_f8f6f4(
                    pf, v1, oacc[mt][2*h + 1], 0, 0, 0, 127, 0, 127);
            }
            __builtin_amdgcn_s_setprio(0);
        }
    };

    // ---- prologue: P(0) -> Plds slot0; stage K(1) -> slot1 ----
    {
        short8 ka = *reinterpret_cast<const short8*>(Kb + (size_t)8192 + t*8);
        short8 kb2 = *reinterpret_cast<const short8*>(Kb + (size_t)8192 + 4096 + t*8);
        f32x4 sn[4];
        QKt(&Klds[0], 0, sn);
        EXPK(sn, 0, Plds);
        QKt(&Klds[0], 1, sn);
        EXPK(sn, 1, Plds);
        *reinterpret_cast<short8*>(&Klds[8192 + kc0]) = ka;
        *reinterpret_cast<short8*>(&Klds[8192 + kc1]) = kb2;
    }
    barrier_lgkm();   // P(0), K(1) visible

    // ---- main loop over 128-key tiles ----
    for (int i = 0; i < 31; ++i) {
        const int cur = i & 1, nxt = cur ^ 1;
        const unsigned char* pcur = Plds + cur*16384;
        unsigned char* pnxt = Plds + nxt*16384;
        const int ipre = (i + 2 < 32) ? (i + 2) : 31;

        f32x4 sn[4];
        QKt(&Klds[nxt*8192], 0, sn);      // QK^T(i+1) half0
        EXPK(sn, 0, pnxt);
        QKt(&Klds[nxt*8192], 1, sn);      // QK^T(i+1) half1
        EXPK(sn, 1, pnxt);

        // K(i+2) issue-early (latency hides under PV; LDS write at iter end)
        short8 ka = *reinterpret_cast<const short8*>(Kb + (size_t)ipre*8192 + t*8);
        short8 kb2 = *reinterpret_cast<const short8*>(Kb + (size_t)ipre*8192 + 4096 + t*8);

        PV(pcur, i * 128);                // PV(i), K=128 MX-fp8 MFMA

        *reinterpret_cast<short8*>(&Klds[cur*8192 + kc0]) = ka;   // K(i+2)
        *reinterpret_cast<short8*>(&Klds[cur*8192 + kc1]) = kb2;

        barrier_lgkm();   // LDS-only drain: V/K global loads stay in flight
    }

    // ---- tail: PV(31) ----
    PV(Plds + 16384, 31 * 128);   // 31 & 1 = 1

    // ---- finalize L: cross-lane reduce once; share via LDS ----
    lrun += __shfl_xor(lrun, 16);
    lrun += __shfl_xor(lrun, 32);
    if (lg == 0) Ll[16*wid + lr] = lrun;
    __syncthreads();

    const float alpha = alpha_p[0];
    #pragma unroll
    for (int mt = 0; mt < 8; ++mt) {
        float4 l4 = *reinterpret_cast<const float4*>(&Ll[16*mt + 4*lg]);
        float ar0 = alpha / l4.x, ar1 = alpha / l4.y, ar2 = alpha / l4.z, ar3 = alpha / l4.w;
        #pragma unroll
        for (int ct = 0; ct < 4; ++ct) {
            const int c = 64*wid + 16*ct + lr;
            const size_t base = ((size_t)b*NC + c)*NN + n0 + 16*mt + 4*lg;
            float4 x4 = *reinterpret_cast<const float4*>(x + base);
            float4 o4;
            o4.x = oacc[mt][ct][0] * ar0 + x4.x;
            o4.y = oacc[mt][ct][1] * ar1 + x4.y;
            o4.z = oacc[mt][ct][2] * ar2 + x4.z;
            o4.w = oacc[mt][ct][3] * ar3 + x4.w;
            *reinterpret_cast<float4*>(out + base) = o4;
        }
    }
}

extern "C" void kernel_launch(void* const* d_in, const int* in_sizes, int n_in,
                              void* d_out, int out_size, void* d_ws, size_t ws_size,
                              hipStream_t stream) {
    const float* x     = (const float*)d_in[0];
    const float* wq    = (const float*)d_in[1];
    const float* bq    = (const float*)d_in[2];
    const float* wk    = (const float*)d_in[3];
    const float* bk    = (const float*)d_in[4];
    const float* wv    = (const float*)d_in[5];
    const float* bv    = (const float*)d_in[6];
    const float* alpha = (const float*)d_in[7];

    // ws: QT bf16 4MB | KT bf16 4MB | V fp8 16MB | Wbf 640KB | Mh 2x128KB
    unsigned short* QT = (unsigned short*)d_ws;
    unsigned short* KT = QT + (size_t)NB*NN*ND;
    unsigned char*  V  = (unsigned char*)(KT + (size_t)NB*NN*ND);
    unsigned short* Wbf = (unsigned short*)(V + (size_t)NB*NC*NN);
    float* Mh = (float*)(Wbf + (size_t)640*NC);

    wprep<<<160, 256, 0, stream>>>(wq, wk, wv, Wbf);
    dim3 gA(64, 8);
    qkv_proj<<<gA, 256, 0, stream>>>(x, Wbf, bq, bk, bv, QT, KT, V);
    stats<<<256, 1024, 0, stream>>>(QT, KT, Mh);
    attn<<<NB * (NN/128), 512, 0, stream>>>(QT, KT, V, Mh, x, alpha, (float*)d_out);
}